// Round 13
// baseline (110.195 us; speedup 1.0000x reference)
//
#include <hip/hip_runtime.h>
#include <cstddef>
#include <cstdint>

#define B_    8
#define T_EN_ 512
#define T_DE_ 128
#define D_    512
#define U_    256

#define NBLK  256
#define NTHR  512

// tanh(x) = 1 - 2/(exp2(C*x)+1), C = 2*log2(e)
#define TANH_C 2.8853900817779268f
#define L2E_   1.4426950408889634f
#define TANH_CLAMP 0.99999994f

typedef float f32x4 __attribute__((ext_vector_type(4)));
typedef float f32x2 __attribute__((ext_vector_type(2)));
typedef short s16x8 __attribute__((ext_vector_type(8)));

__device__ __forceinline__ float fast_tanh_clamped(float x) {
  const float e = __builtin_amdgcn_exp2f(x * TANH_C);
  float t = fmaf(-2.0f, __builtin_amdgcn_rcpf(e + 1.0f), 1.0f);
  return fminf(fmaxf(t, -TANH_CLAMP), TANH_CLAMP);
}

// split f32 -> bf16 hi (truncated) + bf16 lo (truncated remainder)
__device__ __forceinline__ void split_bf16(float x, short& hi, short& lo) {
  const unsigned u = __float_as_uint(x);
  hi = (short)(u >> 16);
  const float hf = __uint_as_float(u & 0xffff0000u);
  const float lf = x - hf;
  lo = (short)(__float_as_uint(lf) >> 16);
}

// Device-wide barrier: all NBLK blocks co-resident (1 block/CU enforced by
// 73 KB LDS + launch_bounds(512) => VGPR<=256 => 8 waves/CU fits exactly).
// Counters are zeroed by a hipMemsetAsync before each kernel launch.
__device__ __forceinline__ void gridbar(int* cnt) {
  __syncthreads();                       // drains each thread's vmcnt (stores in L2)
  if (threadIdx.x == 0) {
    __hip_atomic_fetch_add(cnt, 1, __ATOMIC_ACQ_REL, __HIP_MEMORY_SCOPE_AGENT);
    while (__hip_atomic_load(cnt, __ATOMIC_ACQUIRE, __HIP_MEMORY_SCOPE_AGENT) < NBLK) {
      __builtin_amdgcn_s_sleep(8);
    }
  }
  __syncthreads();
}

// ---------------------------------------------------------------------------
// Fused kernel: [W] prepack -> bar -> [P] MFMA projections+tanh -> bar ->
// [K] tanh-identity attention + masked softmax.  All compute bodies are the
// r11-verified versions; only the work decomposition changed.
// ---------------------------------------------------------------------------
__global__ __launch_bounds__(512) void fused_attention_kernel(
    const float* __restrict__ en, const float* __restrict__ de,
    const float* __restrict__ w_en, const float* __restrict__ w_de,
    const float* __restrict__ nu, const int* __restrict__ mask,
    short* __restrict__ en_hi, short* __restrict__ en_lo,
    short* __restrict__ de_hi, short* __restrict__ de_lo,
    short* __restrict__ wen_hi, short* __restrict__ wen_lo,
    short* __restrict__ wde_hi, short* __restrict__ wde_lo,
    float* __restrict__ Et, float* __restrict__ de_t,
    float* __restrict__ out, int* bar) {
  // LDS (phase K only): 8 + 1 + 64 = 73 KB
  __shared__ f32x4 Lp_s[4][U_ / 2];     // per (j-local, u-pair) {A1,A2,An1,An2}
  __shared__ f32x2 nv2_s[U_ / 2];       // {nu1,nu2} per pair
  __shared__ float mu_p[8][4][T_EN_];   // partial logits

  const int lane = threadIdx.x & 63;
  const int rl = lane >> 4, cl = lane & 15;

  // ================= Phase W: prepack (r11 body, grid-strided) =============
  for (int gu = blockIdx.x * NTHR + threadIdx.x; gu < 1408 * 256; gu += NBLK * NTHR) {
    const int blk = gu >> 8;
    const int tid = gu & 255;
    float v[8];
    short *ph, *pl;
    size_t ub;

    if (blk < 1280) {
      const int n = gu & 15;
      const int g = (gu >> 4) & 3;
      const int s = (gu >> 6) & 15;
      const int rb = gu >> 10;
      const float* src;
      if (rb < 256) {
        const int b = rb >> 5, t = rb & 31;
        src = en + ((size_t)rb * 16 + n) * D_;
        ub = ((size_t)((b * 16 + s) * 32 + t) * 4 + g) * 16 + n;
        ph = en_hi; pl = en_lo;
      } else {
        const int t64 = rb - 256;
        src = de + ((size_t)t64 * 16 + n) * D_;
        ub = ((size_t)(s * 64 + t64) * 4 + g) * 16 + n;
        ph = de_hi; pl = de_lo;
      }
      const int kb = s * 32 + g * 4;
      const float4 fa = *(const float4*)(src + kb);
      const float4 fb = *(const float4*)(src + kb + 16);
      v[0] = fa.x; v[1] = fa.y; v[2] = fa.z; v[3] = fa.w;
      v[4] = fb.x; v[5] = fb.y; v[6] = fb.z; v[7] = fb.w;
    } else {
      const int wb = blk - 1280;
      const bool is_en = wb < 64;
      const int wq = wb & 63;
      const int s = wq >> 2, USq = wq & 3;
      const int n = tid & 15;
      const int g = (tid >> 4) & 3;
      const int US = USq * 4 + (tid >> 6);
      const float* W = is_en ? w_en : w_de;
      ph = is_en ? wen_hi : wde_hi;
      pl = is_en ? wen_lo : wde_lo;
      #pragma unroll
      for (int e = 0; e < 8; ++e) {
        const int k = s * 32 + g * 4 + (e & 3) + 16 * (e >> 2);
        v[e] = W[(size_t)k * U_ + US * 16 + n];
      }
      ub = ((size_t)(s * 16 + US) * 4 + g) * 16 + n;
    }

    s16x8 h8, l8;
    #pragma unroll
    for (int e = 0; e < 8; ++e) {
      short h, l;
      split_bf16(v[e], h, l);
      h8[e] = h; l8[e] = l;
    }
    *(s16x8*)(ph + ub * 8) = h8;
    *(s16x8*)(pl + ub * 8) = l8;
  }

  gridbar(bar);

  // ================= Phase P: MFMA projections + tanh ======================
  // 2048 global waves. en-unit per wave (r11 en branch, exact-fit mapping);
  // de quarter-units (single US) on waves 0..1023.
  {
    const int gw = blockIdx.x * 8 + (threadIdx.x >> 6);
    // ---- en unit ----
    {
      const int b = gw >> 8, uh = (gw >> 7) & 1, it = (gw >> 2) & 31, wv = gw & 3;
      const int US0 = uh * 8 + wv * 2;
      f32x4 acc[2] = {};
      s16x8 bufA[6], bufB[6];

#define LOAD_EN(DST, S)                                                   \
      { const size_t oa0 = ((size_t)((S) * 16 + US0) * 64 + lane) * 8;    \
        const size_t ob  = ((size_t)((b * 16 + (S)) * 32 + it) * 64 + lane) * 8; \
        DST[0] = *(const s16x8*)(wen_hi + oa0);                           \
        DST[1] = *(const s16x8*)(wen_lo + oa0);                           \
        DST[2] = *(const s16x8*)(wen_hi + oa0 + 512);                     \
        DST[3] = *(const s16x8*)(wen_lo + oa0 + 512);                     \
        DST[4] = *(const s16x8*)(en_hi + ob);                             \
        DST[5] = *(const s16x8*)(en_lo + ob); }
#define MFMA_EN(S)                                                        \
      { acc[0] = __builtin_amdgcn_mfma_f32_16x16x32_bf16(S[0], S[4], acc[0], 0, 0, 0); \
        acc[0] = __builtin_amdgcn_mfma_f32_16x16x32_bf16(S[0], S[5], acc[0], 0, 0, 0); \
        acc[0] = __builtin_amdgcn_mfma_f32_16x16x32_bf16(S[1], S[4], acc[0], 0, 0, 0); \
        acc[1] = __builtin_amdgcn_mfma_f32_16x16x32_bf16(S[2], S[4], acc[1], 0, 0, 0); \
        acc[1] = __builtin_amdgcn_mfma_f32_16x16x32_bf16(S[2], S[5], acc[1], 0, 0, 0); \
        acc[1] = __builtin_amdgcn_mfma_f32_16x16x32_bf16(S[3], S[4], acc[1], 0, 0, 0); }

      LOAD_EN(bufA, 0)
      for (int s = 0; s < 16; s += 2) {
        LOAD_EN(bufB, s + 1)
        MFMA_EN(bufA)
        if (s + 2 < 16) LOAD_EN(bufA, s + 2)
        MFMA_EN(bufB)
      }
#undef LOAD_EN
#undef MFMA_EN

      #pragma unroll
      for (int us = 0; us < 2; ++us) {
        #pragma unroll
        for (int r = 0; r < 4; ++r) {
          const int u = (US0 + us) * 16 + rl * 4 + r;
          const int i = it * 16 + cl;
          Et[((size_t)b * U_ + u) * T_EN_ + i] = fast_tanh_clamped(acc[us][r]);
        }
      }
    }
    // ---- de quarter unit (16 j x 16 u) ----
    if (gw < 1024) {
      const int t64 = gw >> 4;          // 0..63
      const int US  = gw & 15;          // 0..15
      f32x4 acc = {};
      #pragma unroll 2
      for (int s = 0; s < 16; ++s) {
        const size_t oa = ((size_t)(s * 64 + t64) * 64 + lane) * 8;
        const size_t ob = ((size_t)(s * 16 + US) * 64 + lane) * 8;
        const s16x8 ah = *(const s16x8*)(de_hi + oa);
        const s16x8 al = *(const s16x8*)(de_lo + oa);
        const s16x8 wh = *(const s16x8*)(wde_hi + ob);
        const s16x8 wl = *(const s16x8*)(wde_lo + ob);
        acc = __builtin_amdgcn_mfma_f32_16x16x32_bf16(ah, wh, acc, 0, 0, 0);
        acc = __builtin_amdgcn_mfma_f32_16x16x32_bf16(ah, wl, acc, 0, 0, 0);
        acc = __builtin_amdgcn_mfma_f32_16x16x32_bf16(al, wh, acc, 0, 0, 0);
      }
      #pragma unroll
      for (int r = 0; r < 4; ++r) {
        const int j = t64 * 16 + rl * 4 + r;
        const int u = US * 16 + cl;
        de_t[(size_t)j * U_ + u] = fast_tanh_clamped(acc[r]);
      }
    }
  }

  gridbar(bar + 1);

  // ================= Phase K: K2 v6 (r11-verified, verbatim) ===============
  {
    const int tid  = threadIdx.x;
    const int kw   = tid >> 6;           // u-octant 0..7
    const int b    = blockIdx.x & 7;
    const int jg   = blockIdx.x >> 3;    // 0..31
    const int j0   = jg * 4;

    // prologue: per-(j, u-pair) constants
    {
      const int jl = tid >> 7;           // 0..3
      const int p  = tid & 127;
      const float2 Av = *(const float2*)(de_t + (size_t)(b * T_DE_ + j0 + jl) * U_ + 2 * p);
      const float2 nv = *(const float2*)(nu + 2 * p);
      f32x4 L;
      L[0] = Av.x; L[1] = Av.y; L[2] = nv.x * Av.x; L[3] = nv.y * Av.y;
      Lp_s[jl][p] = L;
      if (tid < 128) {
        const float2 n2 = *(const float2*)(nu + 2 * tid);
        f32x2 v; v[0] = n2.x; v[1] = n2.y;
        nv2_s[tid] = v;
      }
    }
    __syncthreads();

    const int pb = kw * 16;              // this wave's 16 pairs (32 u)
    const float* __restrict__ EbA =
        Et + ((size_t)b * U_ + 2 * pb) * T_EN_ + lane * 4;

    const f32x4 one4 = {1.f, 1.f, 1.f, 1.f};
    f32x4 accA[4] = {}, accB[4] = {};    // [j-local] x {i-quad A, B}

    f32x4 E1Aa, E1Ba, E2Aa, E2Ba, E1Ab, E1Bb, E2Ab, E2Bb;
    f32x4 La[4], Lb[4];
    f32x2 nva, nvb;

#define LOADP(SUF, P)                                                     \
    { const float* e1 = EbA + (size_t)(2 * (P)) * T_EN_;                  \
      const float* e2 = e1 + T_EN_;                                       \
      E1A##SUF = *(const f32x4*)(e1);                                     \
      E1B##SUF = *(const f32x4*)(e1 + 256);                               \
      E2A##SUF = *(const f32x4*)(e2);                                     \
      E2B##SUF = *(const f32x4*)(e2 + 256);                               \
      L##SUF[0] = Lp_s[0][pb + (P)];                                      \
      L##SUF[1] = Lp_s[1][pb + (P)];                                      \
      L##SUF[2] = Lp_s[2][pb + (P)];                                      \
      L##SUF[3] = Lp_s[3][pb + (P)];                                      \
      nv##SUF = nv2_s[pb + (P)]; }

#define COMPP(SUF)                                                        \
    { const f32x4 T1A = E1A##SUF * nv##SUF[0];                            \
      const f32x4 T1B = E1B##SUF * nv##SUF[0];                            \
      const f32x4 T2A = E2A##SUF * nv##SUF[1];                            \
      const f32x4 T2B = E2B##SUF * nv##SUF[1];                            \
      _Pragma("unroll")                                                   \
      for (int jl = 0; jl < 4; ++jl) {                                    \
        const f32x4 Lc = L##SUF[jl];                                      \
        { const f32x4 d1 = E1A##SUF * Lc[0] + one4;                       \
          const f32x4 d2 = E2A##SUF * Lc[1] + one4;                       \
          const f32x4 n1 = T1A + Lc[2];                                   \
          const f32x4 n2 = T2A + Lc[3];                                   \
          const f32x4 Nn = n1 * d2 + n2 * d1;                             \
          const f32x4 Dd = d1 * d2;                                       \
          f32x4 r;                                                        \
          r[0] = __builtin_amdgcn_rcpf(Dd[0]);                            \
          r[1] = __builtin_amdgcn_rcpf(Dd[1]);                            \
          r[2] = __builtin_amdgcn_rcpf(Dd[2]);                            \
          r[3] = __builtin_amdgcn_rcpf(Dd[3]);                            \
          accA[jl] = Nn * r + accA[jl]; }                                 \
        { const f32x4 d1 = E1B##SUF * Lc[0] + one4;                       \
          const f32x4 d2 = E2B##SUF * Lc[1] + one4;                       \
          const f32x4 n1 = T1B + Lc[2];                                   \
          const f32x4 n2 = T2B + Lc[3];                                   \
          const f32x4 Nn = n1 * d2 + n2 * d1;                             \
          const f32x4 Dd = d1 * d2;                                       \
          f32x4 r;                                                        \
          r[0] = __builtin_amdgcn_rcpf(Dd[0]);                            \
          r[1] = __builtin_amdgcn_rcpf(Dd[1]);                            \
          r[2] = __builtin_amdgcn_rcpf(Dd[2]);                            \
          r[3] = __builtin_amdgcn_rcpf(Dd[3]);                            \
          accB[jl] = Nn * r + accB[jl]; }                                 \
      } }

    LOADP(a, 0)
    for (int p0 = 0; p0 < 16; p0 += 2) {
      LOADP(b, p0 + 1)
      COMPP(a)
      if (p0 + 2 < 16) LOADP(a, p0 + 2)
      COMPP(b)
    }
#undef LOADP
#undef COMPP

    #pragma unroll
    for (int jl = 0; jl < 4; ++jl) {
      *(f32x4*)&mu_p[kw][jl][lane * 4] = accA[jl];
      *(f32x4*)&mu_p[kw][jl][256 + lane * 4] = accB[jl];
    }
    __syncthreads();

    // combine 8 u-octant partials + masked softmax: waves 0..3, one j each
    if (kw < 4) {
      float vals[8];
      float mx = -3.0e38f;
      #pragma unroll
      for (int h = 0; h < 2; ++h) {
        f32x4 s = {0.f, 0.f, 0.f, 0.f};
        #pragma unroll
        for (int uo = 0; uo < 8; ++uo)
          s += *(const f32x4*)&mu_p[uo][kw][h * 256 + lane * 4];
        const int4 mk = *(const int4*)(mask + b * T_EN_ + h * 256 + lane * 4);
        const float v0 = fmaf((float)mk.x - 1.f, 1.0e6f, s[0]);
        const float v1 = fmaf((float)mk.y - 1.f, 1.0e6f, s[1]);
        const float v2 = fmaf((float)mk.z - 1.f, 1.0e6f, s[2]);
        const float v3 = fmaf((float)mk.w - 1.f, 1.0e6f, s[3]);
        vals[h * 4 + 0] = v0; vals[h * 4 + 1] = v1;
        vals[h * 4 + 2] = v2; vals[h * 4 + 3] = v3;
        mx = fmaxf(mx, fmaxf(fmaxf(v0, v1), fmaxf(v2, v3)));
      }
      #pragma unroll
      for (int off = 32; off; off >>= 1) mx = fmaxf(mx, __shfl_xor(mx, off, 64));
      float sum = 0.0f;
      #pragma unroll
      for (int k = 0; k < 8; ++k) {
        const float e = __builtin_amdgcn_exp2f((vals[k] - mx) * L2E_);
        vals[k] = e;
        sum += e;
      }
      #pragma unroll
      for (int off = 32; off; off >>= 1) sum += __shfl_xor(sum, off, 64);
      const float inv = __builtin_amdgcn_rcpf(sum);
      float* op = out + (size_t)(b * T_DE_ + j0 + kw) * T_EN_;
      #pragma unroll
      for (int h = 0; h < 2; ++h) {
        const float4 o = make_float4(vals[h * 4 + 0] * inv, vals[h * 4 + 1] * inv,
                                     vals[h * 4 + 2] * inv, vals[h * 4 + 3] * inv);
        *(float4*)(op + h * 256 + lane * 4) = o;
      }
    }
  }
}

// ---------------------------------------------------------------------------
extern "C" void kernel_launch(void* const* d_in, const int* in_sizes, int n_in,
                              void* d_out, int out_size, void* d_ws, size_t ws_size,
                              hipStream_t stream) {
  const float* en   = (const float*)d_in[0];   // [B, T_EN, D]
  const float* de   = (const float*)d_in[1];   // [B, T_DE, D]
  const int*   mask = (const int*)d_in[2];     // [B, T_EN]
  const float* w_en = (const float*)d_in[3];   // [D, U]
  const float* w_de = (const float*)d_in[4];   // [D, U]
  const float* nu   = (const float*)d_in[5];   // [U, 1]
  float* out = (float*)d_out;                  // [B, T_DE, T_EN]

  // ws layout (~16 MB + 8 B barrier)
  float* Et   = (float*)d_ws;                  // [B][U][T_EN]  4 MB
  float* de_t = Et + (size_t)B_ * U_ * T_EN_;  // [B*T_DE][U]   1 MB
  short* p    = (short*)(de_t + (size_t)B_ * T_DE_ * U_);
  short* en_hi = p;                 p += 2097152;   // B*T_EN*D
  short* en_lo = p;                 p += 2097152;
  short* de_hi = p;                 p += 524288;    // B*T_DE*D
  short* de_lo = p;                 p += 524288;
  short* wen_hi = p;                p += 131072;    // D*U
  short* wen_lo = p;                p += 131072;
  short* wde_hi = p;                p += 131072;
  short* wde_lo = p;                p += 131072;
  int* bar = (int*)p;                               // 2 counters

  hipMemsetAsync(bar, 0, 2 * sizeof(int), stream);
  fused_attention_kernel<<<dim3(NBLK), dim3(NTHR), 0, stream>>>(
      en, de, w_en, w_de, nu, mask,
      en_hi, en_lo, de_hi, de_lo, wen_hi, wen_lo, wde_hi, wde_lo,
      Et, de_t, out, bar);
}

// Round 14
// 39.183 us; speedup vs baseline: 2.8123x; 2.8123x over previous
//
#include <hip/hip_runtime.h>
#include <cstddef>
#include <cstdint>

#define B_    8
#define T_EN_ 512
#define T_DE_ 128
#define D_    512
#define U_    256

// exp(2x) = 2^(C*x), C = 2*log2(e); tanh(a+e) = 1 - 2/(exp(2a)exp(2e)+1)
#define TANH_C 2.8853900817779268f
#define L2E_   1.4426950408889634f

typedef float f32x4 __attribute__((ext_vector_type(4)));
typedef float f32x2 __attribute__((ext_vector_type(2)));
typedef short s16x8 __attribute__((ext_vector_type(8)));

// proj epilogue: store exp(2*acc) (positive, d=EA*EB+1 >= 1 downstream)
__device__ __forceinline__ float exp2c(float x) {
  return __builtin_amdgcn_exp2f(x * TANH_C);
}

// split f32 -> bf16 hi (truncated) + bf16 lo (truncated remainder)
__device__ __forceinline__ void split_bf16(float x, short& hi, short& lo) {
  const unsigned u = __float_as_uint(x);
  hi = (short)(u >> 16);
  const float hf = __uint_as_float(u & 0xffff0000u);
  const float lf = x - hf;
  lo = (short)(__float_as_uint(lf) >> 16);
}

// ---------------------------------------------------------------------------
// Prepack (r5/r6/r11-verified, verbatim): en/de/w_en/w_de -> bf16 hi/lo frag
// planes. k-map in 32-k step s: k = s*32 + g*4 + (e&3) + 16*(e>>2), lane=g*16+n.
// ---------------------------------------------------------------------------
__global__ __launch_bounds__(256) void prepack_kernel(
    const float* __restrict__ en, const float* __restrict__ de,
    const float* __restrict__ w_en, const float* __restrict__ w_de,
    short* __restrict__ en_hi, short* __restrict__ en_lo,
    short* __restrict__ de_hi, short* __restrict__ de_lo,
    short* __restrict__ wen_hi, short* __restrict__ wen_lo,
    short* __restrict__ wde_hi, short* __restrict__ wde_lo) {
  const int blk = blockIdx.x;
  const int tid = threadIdx.x;
  float v[8];
  short* ph;
  short* pl;
  size_t ub;

  if (blk < 1280) {
    const int gu = blk * 256 + tid;
    const int n = gu & 15;
    const int g = (gu >> 4) & 3;
    const int s = (gu >> 6) & 15;
    const int rb = gu >> 10;
    const float* src;
    if (rb < 256) {
      const int b = rb >> 5, t = rb & 31;
      src = en + ((size_t)rb * 16 + n) * D_;
      ub = ((size_t)((b * 16 + s) * 32 + t) * 4 + g) * 16 + n;
      ph = en_hi; pl = en_lo;
    } else {
      const int t64 = rb - 256;
      src = de + ((size_t)t64 * 16 + n) * D_;
      ub = ((size_t)(s * 64 + t64) * 4 + g) * 16 + n;
      ph = de_hi; pl = de_lo;
    }
    const int kb = s * 32 + g * 4;
    const float4 fa = *(const float4*)(src + kb);
    const float4 fb = *(const float4*)(src + kb + 16);
    v[0] = fa.x; v[1] = fa.y; v[2] = fa.z; v[3] = fa.w;
    v[4] = fb.x; v[5] = fb.y; v[6] = fb.z; v[7] = fb.w;
  } else {
    const int wb = blk - 1280;
    const bool is_en = wb < 64;
    const int wq = wb & 63;
    const int s = wq >> 2, USq = wq & 3;
    const int n = tid & 15;
    const int g = (tid >> 4) & 3;
    const int US = USq * 4 + (tid >> 6);
    const float* W = is_en ? w_en : w_de;
    ph = is_en ? wen_hi : wde_hi;
    pl = is_en ? wen_lo : wde_lo;
    #pragma unroll
    for (int e = 0; e < 8; ++e) {
      const int k = s * 32 + g * 4 + (e & 3) + 16 * (e >> 2);
      v[e] = W[(size_t)k * U_ + US * 16 + n];
    }
    ub = ((size_t)(s * 16 + US) * 4 + g) * 16 + n;
  }

  s16x8 h8, l8;
  #pragma unroll
  for (int e = 0; e < 8; ++e) {
    short h, l;
    split_bf16(v[e], h, l);
    h8[e] = h; l8[e] = l;
  }
  *(s16x8*)(ph + ub * 8) = h8;
  *(s16x8*)(pl + ub * 8) = l8;
}

// ---------------------------------------------------------------------------
// K1: MFMA projections (r6/r11-verified structure, verbatim) with exp(2x)
// epilogue instead of tanh: Et = exp(2*en@w_en)^T, de_t = exp(2*de@w_de).
// 640 blocks x 256 thr; pure-global frag loads, 2-stage prefetch, no LDS.
// ---------------------------------------------------------------------------
__global__ __launch_bounds__(256) void mfma_proj_kernel(
    const short* __restrict__ en_hi, const short* __restrict__ en_lo,
    const short* __restrict__ de_hi, const short* __restrict__ de_lo,
    const short* __restrict__ wen_hi, const short* __restrict__ wen_lo,
    const short* __restrict__ wde_hi, const short* __restrict__ wde_lo,
    float* __restrict__ Et, float* __restrict__ de_t) {
  const int blk = blockIdx.x;
  const int tid = threadIdx.x;
  const int lane = tid & 63;
  const int wv = tid >> 6;
  const int rl = lane >> 4, cl = lane & 15;

  f32x4 acc[2] = {};
  s16x8 bufA[6], bufB[6];

  if (blk < 512) {
    const int b  = blk >> 6;
    const int uh = (blk >> 5) & 1;
    const int it = blk & 31;
    const int US0 = uh * 8 + wv * 2;

#define LOAD_EN(DST, S)                                                   \
    { const size_t oa0 = ((size_t)((S) * 16 + US0) * 64 + lane) * 8;      \
      const size_t ob  = ((size_t)((b * 16 + (S)) * 32 + it) * 64 + lane) * 8; \
      DST[0] = *(const s16x8*)(wen_hi + oa0);                             \
      DST[1] = *(const s16x8*)(wen_lo + oa0);                             \
      DST[2] = *(const s16x8*)(wen_hi + oa0 + 512);                       \
      DST[3] = *(const s16x8*)(wen_lo + oa0 + 512);                       \
      DST[4] = *(const s16x8*)(en_hi + ob);                               \
      DST[5] = *(const s16x8*)(en_lo + ob); }
#define MFMA_EN(S)                                                        \
    { acc[0] = __builtin_amdgcn_mfma_f32_16x16x32_bf16(S[0], S[4], acc[0], 0, 0, 0); \
      acc[0] = __builtin_amdgcn_mfma_f32_16x16x32_bf16(S[0], S[5], acc[0], 0, 0, 0); \
      acc[0] = __builtin_amdgcn_mfma_f32_16x16x32_bf16(S[1], S[4], acc[0], 0, 0, 0); \
      acc[1] = __builtin_amdgcn_mfma_f32_16x16x32_bf16(S[2], S[4], acc[1], 0, 0, 0); \
      acc[1] = __builtin_amdgcn_mfma_f32_16x16x32_bf16(S[2], S[5], acc[1], 0, 0, 0); \
      acc[1] = __builtin_amdgcn_mfma_f32_16x16x32_bf16(S[3], S[4], acc[1], 0, 0, 0); }

    LOAD_EN(bufA, 0)
    for (int s = 0; s < 16; s += 2) {
      LOAD_EN(bufB, s + 1)
      MFMA_EN(bufA)
      if (s + 2 < 16) LOAD_EN(bufA, s + 2)
      MFMA_EN(bufB)
    }
#undef LOAD_EN
#undef MFMA_EN

    #pragma unroll
    for (int us = 0; us < 2; ++us) {
      #pragma unroll
      for (int r = 0; r < 4; ++r) {
        const int u = (US0 + us) * 16 + rl * 4 + r;
        const int i = it * 16 + cl;
        Et[((size_t)b * U_ + u) * T_EN_ + i] = exp2c(acc[us][r]);
      }
    }
  } else {
    const int y = blk - 512;
    const int t64 = y >> 1;
    const int uh = y & 1;
    const int US0 = uh * 8 + wv * 2;

#define LOAD_DE(DST, S)                                                   \
    { const size_t oa = ((size_t)((S) * 64 + t64) * 64 + lane) * 8;       \
      const size_t ob = ((size_t)((S) * 16 + US0) * 64 + lane) * 8;       \
      DST[0] = *(const s16x8*)(de_hi + oa);                               \
      DST[1] = *(const s16x8*)(de_lo + oa);                               \
      DST[2] = *(const s16x8*)(wde_hi + ob);                              \
      DST[3] = *(const s16x8*)(wde_lo + ob);                              \
      DST[4] = *(const s16x8*)(wde_hi + ob + 512);                        \
      DST[5] = *(const s16x8*)(wde_lo + ob + 512); }
#define MFMA_DE(S)                                                        \
    { acc[0] = __builtin_amdgcn_mfma_f32_16x16x32_bf16(S[0], S[2], acc[0], 0, 0, 0); \
      acc[0] = __builtin_amdgcn_mfma_f32_16x16x32_bf16(S[0], S[3], acc[0], 0, 0, 0); \
      acc[0] = __builtin_amdgcn_mfma_f32_16x16x32_bf16(S[1], S[2], acc[0], 0, 0, 0); \
      acc[1] = __builtin_amdgcn_mfma_f32_16x16x32_bf16(S[0], S[4], acc[1], 0, 0, 0); \
      acc[1] = __builtin_amdgcn_mfma_f32_16x16x32_bf16(S[0], S[5], acc[1], 0, 0, 0); \
      acc[1] = __builtin_amdgcn_mfma_f32_16x16x32_bf16(S[1], S[4], acc[1], 0, 0, 0); }

    LOAD_DE(bufA, 0)
    for (int s = 0; s < 16; s += 2) {
      LOAD_DE(bufB, s + 1)
      MFMA_DE(bufA)
      if (s + 2 < 16) LOAD_DE(bufA, s + 2)
      MFMA_DE(bufB)
    }
#undef LOAD_DE
#undef MFMA_DE

    #pragma unroll
    for (int us = 0; us < 2; ++us) {
      #pragma unroll
      for (int r = 0; r < 4; ++r) {
        const int j = t64 * 16 + rl * 4 + r;
        const int u = (US0 + us) * 16 + cl;
        de_t[(size_t)j * U_ + u] = exp2c(acc[us][r]);
      }
    }
  }
}

// ---------------------------------------------------------------------------
// K2 v9: exp-product form. mu[j,i] = Snu - 2 * sum_u nu_u / (EA[j,u]*EB[u,i]+1)
// where EA = exp(2*att_de), EB = exp(2*att_en). Per u-pair per (j, i-quad):
//   d1 = EB1*EA1+1, d2 = EB2*EA2+1, num = nu1*d2 + nu2*d1,
//   acc += num * rcp(d1*d2)            [6 f32x4 + 4 rcp for 2u x 4i]
// = 3.5 issue slots/term vs v6's 4.75. d >= 1 always -> no cancellation.
// Skeleton = r11 K2 v6 verbatim: grid 256 = jg*8 + b, 512 thr = 8 u-octant
// waves, 4 j x 512 i per wave, partials mu_p[8][4][512], waves 0..3 softmax.
// ---------------------------------------------------------------------------
__global__ __launch_bounds__(512) void attn_mu_softmax_kernel(
    const float* __restrict__ Et, const float* __restrict__ de_t,
    const float* __restrict__ nu, const int* __restrict__ mask,
    float* __restrict__ out) {
  __shared__ f32x2 Ea_s[4][U_ / 2];     // {EA1,EA2} per (j-local, u-pair) 4 KB
  __shared__ f32x2 nv2_s[U_ / 2];       // {nu1,nu2} per pair, 1 KB
  __shared__ float mu_p[8][4][T_EN_];   // partial sums, 64 KB
  __shared__ float snu_s;               // sum of nu

  const int tid  = threadIdx.x;
  const int lane = tid & 63;
  const int w    = tid >> 6;           // u-octant 0..7
  const int b    = blockIdx.x & 7;
  const int jg   = blockIdx.x >> 3;    // 0..31
  const int j0   = jg * 4;

  // ---- prologue: per-(j, u-pair) constants + Snu ----
  {
    const int jl = tid >> 7;           // 0..3
    const int p  = tid & 127;
    const float2 Av = *(const float2*)(de_t + (size_t)(b * T_DE_ + j0 + jl) * U_ + 2 * p);
    f32x2 L; L[0] = Av.x; L[1] = Av.y;
    Ea_s[jl][p] = L;
    if (tid < 128) {
      const float2 n2 = *(const float2*)(nu + 2 * tid);
      f32x2 v; v[0] = n2.x; v[1] = n2.y;
      nv2_s[tid] = v;
    }
    if (tid < 64) {
      const float4 nq = *(const float4*)(nu + tid * 4);
      float s = (nq.x + nq.y) + (nq.z + nq.w);
      #pragma unroll
      for (int off = 32; off; off >>= 1) s += __shfl_xor(s, off, 64);
      if (tid == 0) snu_s = s;
    }
  }
  __syncthreads();

  const int pb = w * 16;               // this wave's 16 pairs (32 u)
  const float* __restrict__ EbA =
      Et + ((size_t)b * U_ + 2 * pb) * T_EN_ + lane * 4;

  const f32x4 one4 = {1.f, 1.f, 1.f, 1.f};
  f32x4 accA[4] = {}, accB[4] = {};    // [j-local] x {i-quad A, B}

  f32x4 E1Aa, E1Ba, E2Aa, E2Ba, E1Ab, E1Bb, E2Ab, E2Bb;
  f32x2 La[4], Lb[4];
  f32x2 nva, nvb;

#define LOADP(SUF, P)                                                     \
  { const float* e1 = EbA + (size_t)(2 * (P)) * T_EN_;                    \
    const float* e2 = e1 + T_EN_;                                         \
    E1A##SUF = *(const f32x4*)(e1);                                       \
    E1B##SUF = *(const f32x4*)(e1 + 256);                                 \
    E2A##SUF = *(const f32x4*)(e2);                                       \
    E2B##SUF = *(const f32x4*)(e2 + 256);                                 \
    L##SUF[0] = Ea_s[0][pb + (P)];                                        \
    L##SUF[1] = Ea_s[1][pb + (P)];                                        \
    L##SUF[2] = Ea_s[2][pb + (P)];                                        \
    L##SUF[3] = Ea_s[3][pb + (P)];                                        \
    nv##SUF = nv2_s[pb + (P)]; }

#define COMPP(SUF)                                                        \
  { _Pragma("unroll")                                                     \
    for (int jl = 0; jl < 4; ++jl) {                                      \
      const f32x2 Lc = L##SUF[jl];                                        \
      { const f32x4 d1 = E1A##SUF * Lc[0] + one4;                         \
        const f32x4 d2 = E2A##SUF * Lc[1] + one4;                         \
        const f32x4 t  = d2 * nv##SUF[0];                                 \
        const f32x4 num = d1 * nv##SUF[1] + t;                            \
        const f32x4 Dd = d1 * d2;                                         \
        f32x4 r;                                                          \
        r[0] = __builtin_amdgcn_rcpf(Dd[0]);                              \
        r[1] = __builtin_amdgcn_rcpf(Dd[1]);                              \
        r[2] = __builtin_amdgcn_rcpf(Dd[2]);                              \
        r[3] = __builtin_amdgcn_rcpf(Dd[3]);                              \
        accA[jl] = num * r + accA[jl]; }                                  \
      { const f32x4 d1 = E1B##SUF * Lc[0] + one4;                         \
        const f32x4 d2 = E2B##SUF * Lc[1] + one4;                         \
        const f32x4 t  = d2 * nv##SUF[0];                                 \
        const f32x4 num = d1 * nv##SUF[1] + t;                            \
        const f32x4 Dd = d1 * d2;                                         \
        f32x4 r;                                                          \
        r[0] = __builtin_amdgcn_rcpf(Dd[0]);                              \
        r[1] = __builtin_amdgcn_rcpf(Dd[1]);                              \
        r[2] = __builtin_amdgcn_rcpf(Dd[2]);                              \
        r[3] = __builtin_amdgcn_rcpf(Dd[3]);                              \
        accB[jl] = num * r + accB[jl]; }                                  \
    } }

  LOADP(a, 0)
  for (int p0 = 0; p0 < 16; p0 += 2) {
    LOADP(b, p0 + 1)
    COMPP(a)
    if (p0 + 2 < 16) LOADP(a, p0 + 2)
    COMPP(b)
  }
#undef LOADP
#undef COMPP

  #pragma unroll
  for (int jl = 0; jl < 4; ++jl) {
    *(f32x4*)&mu_p[w][jl][lane * 4] = accA[jl];
    *(f32x4*)&mu_p[w][jl][256 + lane * 4] = accB[jl];
  }
  __syncthreads();

  // ---- combine octant partials + masked softmax: waves 0..3, one j each ----
  if (w < 4) {
    const float snu = snu_s;
    float vals[8];
    float mx = -3.0e38f;
    #pragma unroll
    for (int h = 0; h < 2; ++h) {
      f32x4 s = {0.f, 0.f, 0.f, 0.f};
      #pragma unroll
      for (int uo = 0; uo < 8; ++uo)
        s += *(const f32x4*)&mu_p[uo][w][h * 256 + lane * 4];
      const int4 mk = *(const int4*)(mask + b * T_EN_ + h * 256 + lane * 4);
      const float v0 = fmaf((float)mk.x - 1.f, 1.0e6f, fmaf(-2.f, s[0], snu));
      const float v1 = fmaf((float)mk.y - 1.f, 1.0e6f, fmaf(-2.f, s[1], snu));
      const float v2 = fmaf((float)mk.z - 1.f, 1.0e6f, fmaf(-2.f, s[2], snu));
      const float v3 = fmaf((float)mk.w - 1.f, 1.0e6f, fmaf(-2.f, s[3], snu));
      vals[h * 4 + 0] = v0; vals[h * 4 + 1] = v1;
      vals[h * 4 + 2] = v2; vals[h * 4 + 3] = v3;
      mx = fmaxf(mx, fmaxf(fmaxf(v0, v1), fmaxf(v2, v3)));
    }
    #pragma unroll
    for (int off = 32; off; off >>= 1) mx = fmaxf(mx, __shfl_xor(mx, off, 64));
    float sum = 0.0f;
    #pragma unroll
    for (int k = 0; k < 8; ++k) {
      const float e = __builtin_amdgcn_exp2f((vals[k] - mx) * L2E_);
      vals[k] = e;
      sum += e;
    }
    #pragma unroll
    for (int off = 32; off; off >>= 1) sum += __shfl_xor(sum, off, 64);
    const float inv = __builtin_amdgcn_rcpf(sum);
    float* op = out + (size_t)(b * T_DE_ + j0 + w) * T_EN_;
    #pragma unroll
    for (int h = 0; h < 2; ++h) {
      const float4 o = make_float4(vals[h * 4 + 0] * inv, vals[h * 4 + 1] * inv,
                                   vals[h * 4 + 2] * inv, vals[h * 4 + 3] * inv);
      *(float4*)(op + h * 256 + lane * 4) = o;
    }
  }
}

// ---------------------------------------------------------------------------
extern "C" void kernel_launch(void* const* d_in, const int* in_sizes, int n_in,
                              void* d_out, int out_size, void* d_ws, size_t ws_size,
                              hipStream_t stream) {
  const float* en   = (const float*)d_in[0];   // [B, T_EN, D]
  const float* de   = (const float*)d_in[1];   // [B, T_DE, D]
  const int*   mask = (const int*)d_in[2];     // [B, T_EN]
  const float* w_en = (const float*)d_in[3];   // [D, U]
  const float* w_de = (const float*)d_in[4];   // [D, U]
  const float* nu   = (const float*)d_in[5];   // [U, 1]
  float* out = (float*)d_out;                  // [B, T_DE, T_EN]

  // ws layout (16 MB; verified available since r5)
  float* Et   = (float*)d_ws;                  // exp(2*en@w_en)^T [B][U][T_EN]
  float* de_t = Et + (size_t)B_ * U_ * T_EN_;  // exp(2*de@w_de)   [B*T_DE][U]
  short* p    = (short*)(de_t + (size_t)B_ * T_DE_ * U_);
  short* en_hi = p;                 p += 2097152;   // B*T_EN*D
  short* en_lo = p;                 p += 2097152;
  short* de_hi = p;                 p += 524288;    // B*T_DE*D
  short* de_lo = p;                 p += 524288;
  short* wen_hi = p;                p += 131072;    // D*U
  short* wen_lo = p;                p += 131072;
  short* wde_hi = p;                p += 131072;
  short* wde_lo = p;                p += 131072;

  prepack_kernel<<<dim3(1408), 256, 0, stream>>>(
      en, de, w_en, w_de, en_hi, en_lo, de_hi, de_lo,
      wen_hi, wen_lo, wde_hi, wde_lo);
  mfma_proj_kernel<<<dim3(640), 256, 0, stream>>>(
      en_hi, en_lo, de_hi, de_lo, wen_hi, wen_lo, wde_hi, wde_lo, Et, de_t);
  attn_mu_softmax_kernel<<<dim3(256), 512, 0, stream>>>(
      Et, de_t, nu, mask, out);
}

// Round 15
// 38.997 us; speedup vs baseline: 2.8257x; 1.0048x over previous
//
#include <hip/hip_runtime.h>
#include <cstddef>
#include <cstdint>

#define B_    8
#define T_EN_ 512
#define T_DE_ 128
#define D_    512
#define U_    256

// exp(2x) = 2^(C*x), C = 2*log2(e); tanh(a+e) = 1 - 2/(exp(2a)exp(2e)+1)
#define TANH_C 2.8853900817779268f
#define L2E_   1.4426950408889634f

typedef float f32x4 __attribute__((ext_vector_type(4)));
typedef float f32x2 __attribute__((ext_vector_type(2)));
typedef short s16x8 __attribute__((ext_vector_type(8)));

// proj epilogue: store exp(2*acc) (positive, d=EA*EB+1 >= 1 downstream)
__device__ __forceinline__ float exp2c(float x) {
  return __builtin_amdgcn_exp2f(x * TANH_C);
}

// split f32 -> bf16 hi (truncated) + bf16 lo (truncated remainder)
__device__ __forceinline__ void split_bf16(float x, short& hi, short& lo) {
  const unsigned u = __float_as_uint(x);
  hi = (short)(u >> 16);
  const float hf = __uint_as_float(u & 0xffff0000u);
  const float lf = x - hf;
  lo = (short)(__float_as_uint(lf) >> 16);
}

// ---------------------------------------------------------------------------
// Prepack (r5-r14-verified, verbatim): en/de/w_en/w_de -> bf16 hi/lo frag
// planes. k-map in 32-k step s: k = s*32 + g*4 + (e&3) + 16*(e>>2), lane=g*16+n.
// ---------------------------------------------------------------------------
__global__ __launch_bounds__(256) void prepack_kernel(
    const float* __restrict__ en, const float* __restrict__ de,
    const float* __restrict__ w_en, const float* __restrict__ w_de,
    short* __restrict__ en_hi, short* __restrict__ en_lo,
    short* __restrict__ de_hi, short* __restrict__ de_lo,
    short* __restrict__ wen_hi, short* __restrict__ wen_lo,
    short* __restrict__ wde_hi, short* __restrict__ wde_lo) {
  const int blk = blockIdx.x;
  const int tid = threadIdx.x;
  float v[8];
  short* ph;
  short* pl;
  size_t ub;

  if (blk < 1280) {
    const int gu = blk * 256 + tid;
    const int n = gu & 15;
    const int g = (gu >> 4) & 3;
    const int s = (gu >> 6) & 15;
    const int rb = gu >> 10;
    const float* src;
    if (rb < 256) {
      const int b = rb >> 5, t = rb & 31;
      src = en + ((size_t)rb * 16 + n) * D_;
      ub = ((size_t)((b * 16 + s) * 32 + t) * 4 + g) * 16 + n;
      ph = en_hi; pl = en_lo;
    } else {
      const int t64 = rb - 256;
      src = de + ((size_t)t64 * 16 + n) * D_;
      ub = ((size_t)(s * 64 + t64) * 4 + g) * 16 + n;
      ph = de_hi; pl = de_lo;
    }
    const int kb = s * 32 + g * 4;
    const float4 fa = *(const float4*)(src + kb);
    const float4 fb = *(const float4*)(src + kb + 16);
    v[0] = fa.x; v[1] = fa.y; v[2] = fa.z; v[3] = fa.w;
    v[4] = fb.x; v[5] = fb.y; v[6] = fb.z; v[7] = fb.w;
  } else {
    const int wb = blk - 1280;
    const bool is_en = wb < 64;
    const int wq = wb & 63;
    const int s = wq >> 2, USq = wq & 3;
    const int n = tid & 15;
    const int g = (tid >> 4) & 3;
    const int US = USq * 4 + (tid >> 6);
    const float* W = is_en ? w_en : w_de;
    ph = is_en ? wen_hi : wde_hi;
    pl = is_en ? wen_lo : wde_lo;
    #pragma unroll
    for (int e = 0; e < 8; ++e) {
      const int k = s * 32 + g * 4 + (e & 3) + 16 * (e >> 2);
      v[e] = W[(size_t)k * U_ + US * 16 + n];
    }
    ub = ((size_t)(s * 16 + US) * 4 + g) * 16 + n;
  }

  s16x8 h8, l8;
  #pragma unroll
  for (int e = 0; e < 8; ++e) {
    short h, l;
    split_bf16(v[e], h, l);
    h8[e] = h; l8[e] = l;
  }
  *(s16x8*)(ph + ub * 8) = h8;
  *(s16x8*)(pl + ub * 8) = l8;
}

// ---------------------------------------------------------------------------
// K1: MFMA projections + exp(2x) epilogue (r14-verified bodies).
// XCD CHANGE (r15): en-branch block decode is now b = blk&7 so the blocks
// writing Et[b] run on XCD b -- matching K2's reader pinning (blockIdx&7 = b).
// Et[b] then stays in XCD-b L2 (write-back) and K2's 134 MB of E-reads are
// L2 hits instead of L3. Per-block work/indices unchanged.
// ---------------------------------------------------------------------------
__global__ __launch_bounds__(256) void mfma_proj_kernel(
    const short* __restrict__ en_hi, const short* __restrict__ en_lo,
    const short* __restrict__ de_hi, const short* __restrict__ de_lo,
    const short* __restrict__ wen_hi, const short* __restrict__ wen_lo,
    const short* __restrict__ wde_hi, const short* __restrict__ wde_lo,
    float* __restrict__ Et, float* __restrict__ de_t) {
  const int blk = blockIdx.x;
  const int tid = threadIdx.x;
  const int lane = tid & 63;
  const int wv = tid >> 6;
  const int rl = lane >> 4, cl = lane & 15;

  f32x4 acc[2] = {};
  s16x8 bufA[6], bufB[6];

  if (blk < 512) {
    const int b  = blk & 7;            // XCD-pinned: XCD(blk)=blk%8=b
    const int uh = (blk >> 3) & 1;
    const int it = blk >> 4;           // 0..31
    const int US0 = uh * 8 + wv * 2;

#define LOAD_EN(DST, S)                                                   \
    { const size_t oa0 = ((size_t)((S) * 16 + US0) * 64 + lane) * 8;      \
      const size_t ob  = ((size_t)((b * 16 + (S)) * 32 + it) * 64 + lane) * 8; \
      DST[0] = *(const s16x8*)(wen_hi + oa0);                             \
      DST[1] = *(const s16x8*)(wen_lo + oa0);                             \
      DST[2] = *(const s16x8*)(wen_hi + oa0 + 512);                       \
      DST[3] = *(const s16x8*)(wen_lo + oa0 + 512);                       \
      DST[4] = *(const s16x8*)(en_hi + ob);                               \
      DST[5] = *(const s16x8*)(en_lo + ob); }
#define MFMA_EN(S)                                                        \
    { acc[0] = __builtin_amdgcn_mfma_f32_16x16x32_bf16(S[0], S[4], acc[0], 0, 0, 0); \
      acc[0] = __builtin_amdgcn_mfma_f32_16x16x32_bf16(S[0], S[5], acc[0], 0, 0, 0); \
      acc[0] = __builtin_amdgcn_mfma_f32_16x16x32_bf16(S[1], S[4], acc[0], 0, 0, 0); \
      acc[1] = __builtin_amdgcn_mfma_f32_16x16x32_bf16(S[2], S[4], acc[1], 0, 0, 0); \
      acc[1] = __builtin_amdgcn_mfma_f32_16x16x32_bf16(S[2], S[5], acc[1], 0, 0, 0); \
      acc[1] = __builtin_amdgcn_mfma_f32_16x16x32_bf16(S[3], S[4], acc[1], 0, 0, 0); }

    LOAD_EN(bufA, 0)
    for (int s = 0; s < 16; s += 2) {
      LOAD_EN(bufB, s + 1)
      MFMA_EN(bufA)
      if (s + 2 < 16) LOAD_EN(bufA, s + 2)
      MFMA_EN(bufB)
    }
#undef LOAD_EN
#undef MFMA_EN

    #pragma unroll
    for (int us = 0; us < 2; ++us) {
      #pragma unroll
      for (int r = 0; r < 4; ++r) {
        const int u = (US0 + us) * 16 + rl * 4 + r;
        const int i = it * 16 + cl;
        Et[((size_t)b * U_ + u) * T_EN_ + i] = exp2c(acc[us][r]);
      }
    }
  } else {
    const int y = blk - 512;
    const int t64 = y >> 1;
    const int uh = y & 1;
    const int US0 = uh * 8 + wv * 2;

#define LOAD_DE(DST, S)                                                   \
    { const size_t oa = ((size_t)((S) * 64 + t64) * 64 + lane) * 8;       \
      const size_t ob = ((size_t)((S) * 16 + US0) * 64 + lane) * 8;       \
      DST[0] = *(const s16x8*)(de_hi + oa);                               \
      DST[1] = *(const s16x8*)(de_lo + oa);                               \
      DST[2] = *(const s16x8*)(wde_hi + ob);                              \
      DST[3] = *(const s16x8*)(wde_lo + ob);                              \
      DST[4] = *(const s16x8*)(wde_hi + ob + 512);                        \
      DST[5] = *(const s16x8*)(wde_lo + ob + 512); }
#define MFMA_DE(S)                                                        \
    { acc[0] = __builtin_amdgcn_mfma_f32_16x16x32_bf16(S[0], S[2], acc[0], 0, 0, 0); \
      acc[0] = __builtin_amdgcn_mfma_f32_16x16x32_bf16(S[0], S[3], acc[0], 0, 0, 0); \
      acc[0] = __builtin_amdgcn_mfma_f32_16x16x32_bf16(S[1], S[2], acc[0], 0, 0, 0); \
      acc[1] = __builtin_amdgcn_mfma_f32_16x16x32_bf16(S[0], S[4], acc[1], 0, 0, 0); \
      acc[1] = __builtin_amdgcn_mfma_f32_16x16x32_bf16(S[0], S[5], acc[1], 0, 0, 0); \
      acc[1] = __builtin_amdgcn_mfma_f32_16x16x32_bf16(S[1], S[4], acc[1], 0, 0, 0); }

    LOAD_DE(bufA, 0)
    for (int s = 0; s < 16; s += 2) {
      LOAD_DE(bufB, s + 1)
      MFMA_DE(bufA)
      if (s + 2 < 16) LOAD_DE(bufA, s + 2)
      MFMA_DE(bufB)
    }
#undef LOAD_DE
#undef MFMA_DE

    #pragma unroll
    for (int us = 0; us < 2; ++us) {
      #pragma unroll
      for (int r = 0; r < 4; ++r) {
        const int j = t64 * 16 + rl * 4 + r;
        const int u = (US0 + us) * 16 + cl;
        de_t[(size_t)j * U_ + u] = exp2c(acc[us][r]);
      }
    }
  }
}

// ---------------------------------------------------------------------------
// K2 v9 (r14-verified): mu' = -2 * sum_u nu_u / (EA[j,u]*EB[u,i]+1)
// (the Snu constant is dropped -- softmax is shift-invariant per row, output
// is bit-identical). Per u-pair per (j, i-quad): d1, d2, num, rcp(d1*d2).
// grid 256 = jg*8 + b (XCD-pinned to match proj's Et writes), 512 thr.
// ---------------------------------------------------------------------------
__global__ __launch_bounds__(512) void attn_mu_softmax_kernel(
    const float* __restrict__ Et, const float* __restrict__ de_t,
    const float* __restrict__ nu, const int* __restrict__ mask,
    float* __restrict__ out) {
  __shared__ f32x2 Ea_s[4][U_ / 2];     // {EA1,EA2} per (j-local, u-pair) 4 KB
  __shared__ f32x2 nv2_s[U_ / 2];       // {nu1,nu2} per pair, 1 KB
  __shared__ float mu_p[8][4][T_EN_];   // partial sums, 64 KB

  const int tid  = threadIdx.x;
  const int lane = tid & 63;
  const int w    = tid >> 6;           // u-octant 0..7
  const int b    = blockIdx.x & 7;
  const int jg   = blockIdx.x >> 3;    // 0..31
  const int j0   = jg * 4;

  // ---- prologue: per-(j, u-pair) constants ----
  {
    const int jl = tid >> 7;           // 0..3
    const int p  = tid & 127;
    const float2 Av = *(const float2*)(de_t + (size_t)(b * T_DE_ + j0 + jl) * U_ + 2 * p);
    f32x2 L; L[0] = Av.x; L[1] = Av.y;
    Ea_s[jl][p] = L;
    if (tid < 128) {
      const float2 n2 = *(const float2*)(nu + 2 * tid);
      f32x2 v; v[0] = n2.x; v[1] = n2.y;
      nv2_s[tid] = v;
    }
  }
  __syncthreads();

  const int pb = w * 16;               // this wave's 16 pairs (32 u)
  const float* __restrict__ EbA =
      Et + ((size_t)b * U_ + 2 * pb) * T_EN_ + lane * 4;

  const f32x4 one4 = {1.f, 1.f, 1.f, 1.f};
  f32x4 accA[4] = {}, accB[4] = {};    // [j-local] x {i-quad A, B}

  f32x4 E1Aa, E1Ba, E2Aa, E2Ba, E1Ab, E1Bb, E2Ab, E2Bb;
  f32x2 La[4], Lb[4];
  f32x2 nva, nvb;

#define LOADP(SUF, P)                                                     \
  { const float* e1 = EbA + (size_t)(2 * (P)) * T_EN_;                    \
    const float* e2 = e1 + T_EN_;                                         \
    E1A##SUF = *(const f32x4*)(e1);                                       \
    E1B##SUF = *(const f32x4*)(e1 + 256);                                 \
    E2A##SUF = *(const f32x4*)(e2);                                       \
    E2B##SUF = *(const f32x4*)(e2 + 256);                                 \
    L##SUF[0] = Ea_s[0][pb + (P)];                                        \
    L##SUF[1] = Ea_s[1][pb + (P)];                                        \
    L##SUF[2] = Ea_s[2][pb + (P)];                                        \
    L##SUF[3] = Ea_s[3][pb + (P)];                                        \
    nv##SUF = nv2_s[pb + (P)]; }

#define COMPP(SUF)                                                        \
  { _Pragma("unroll")                                                     \
    for (int jl = 0; jl < 4; ++jl) {                                      \
      const f32x2 Lc = L##SUF[jl];                                        \
      { const f32x4 d1 = E1A##SUF * Lc[0] + one4;                         \
        const f32x4 d2 = E2A##SUF * Lc[1] + one4;                         \
        const f32x4 t  = d2 * nv##SUF[0];                                 \
        const f32x4 num = d1 * nv##SUF[1] + t;                            \
        const f32x4 Dd = d1 * d2;                                         \
        f32x4 r;                                                          \
        r[0] = __builtin_amdgcn_rcpf(Dd[0]);                              \
        r[1] = __builtin_amdgcn_rcpf(Dd[1]);                              \
        r[2] = __builtin_amdgcn_rcpf(Dd[2]);                              \
        r[3] = __builtin_amdgcn_rcpf(Dd[3]);                              \
        accA[jl] = num * r + accA[jl]; }                                  \
      { const f32x4 d1 = E1B##SUF * Lc[0] + one4;                         \
        const f32x4 d2 = E2B##SUF * Lc[1] + one4;                         \
        const f32x4 t  = d2 * nv##SUF[0];                                 \
        const f32x4 num = d1 * nv##SUF[1] + t;                            \
        const f32x4 Dd = d1 * d2;                                         \
        f32x4 r;                                                          \
        r[0] = __builtin_amdgcn_rcpf(Dd[0]);                              \
        r[1] = __builtin_amdgcn_rcpf(Dd[1]);                              \
        r[2] = __builtin_amdgcn_rcpf(Dd[2]);                              \
        r[3] = __builtin_amdgcn_rcpf(Dd[3]);                              \
        accB[jl] = num * r + accB[jl]; }                                  \
    } }

  LOADP(a, 0)
  for (int p0 = 0; p0 < 16; p0 += 2) {
    LOADP(b, p0 + 1)
    COMPP(a)
    if (p0 + 2 < 16) LOADP(a, p0 + 2)
    COMPP(b)
  }
#undef LOADP
#undef COMPP

  #pragma unroll
  for (int jl = 0; jl < 4; ++jl) {
    *(f32x4*)&mu_p[w][jl][lane * 4] = accA[jl];
    *(f32x4*)&mu_p[w][jl][256 + lane * 4] = accB[jl];
  }
  __syncthreads();

  // ---- combine octant partials + masked softmax: waves 0..3, one j each ----
  if (w < 4) {
    float vals[8];
    float mx = -3.0e38f;
    #pragma unroll
    for (int h = 0; h < 2; ++h) {
      f32x4 s = {0.f, 0.f, 0.f, 0.f};
      #pragma unroll
      for (int uo = 0; uo < 8; ++uo)
        s += *(const f32x4*)&mu_p[uo][w][h * 256 + lane * 4];
      const int4 mk = *(const int4*)(mask + b * T_EN_ + h * 256 + lane * 4);
      const float v0 = fmaf((float)mk.x - 1.f, 1.0e6f, -2.f * s[0]);
      const float v1 = fmaf((float)mk.y - 1.f, 1.0e6f, -2.f * s[1]);
      const float v2 = fmaf((float)mk.z - 1.f, 1.0e6f, -2.f * s[2]);
      const float v3 = fmaf((float)mk.w - 1.f, 1.0e6f, -2.f * s[3]);
      vals[h * 4 + 0] = v0; vals[h * 4 + 1] = v1;
      vals[h * 4 + 2] = v2; vals[h * 4 + 3] = v3;
      mx = fmaxf(mx, fmaxf(fmaxf(v0, v1), fmaxf(v2, v3)));
    }
    #pragma unroll
    for (int off = 32; off; off >>= 1) mx = fmaxf(mx, __shfl_xor(mx, off, 64));
    float sum = 0.0f;
    #pragma unroll
    for (int k = 0; k < 8; ++k) {
      const float e = __builtin_amdgcn_exp2f((vals[k] - mx) * L2E_);
      vals[k] = e;
      sum += e;
    }
    #pragma unroll
    for (int off = 32; off; off >>= 1) sum += __shfl_xor(sum, off, 64);
    const float inv = __builtin_amdgcn_rcpf(sum);
    float* op = out + (size_t)(b * T_DE_ + j0 + w) * T_EN_;
    #pragma unroll
    for (int h = 0; h < 2; ++h) {
      const float4 o = make_float4(vals[h * 4 + 0] * inv, vals[h * 4 + 1] * inv,
                                   vals[h * 4 + 2] * inv, vals[h * 4 + 3] * inv);
      *(float4*)(op + h * 256 + lane * 4) = o;
    }
  }
}

// ---------------------------------------------------------------------------
extern "C" void kernel_launch(void* const* d_in, const int* in_sizes, int n_in,
                              void* d_out, int out_size, void* d_ws, size_t ws_size,
                              hipStream_t stream) {
  const float* en   = (const float*)d_in[0];   // [B, T_EN, D]
  const float* de   = (const float*)d_in[1];   // [B, T_DE, D]
  const int*   mask = (const int*)d_in[2];     // [B, T_EN]
  const float* w_en = (const float*)d_in[3];   // [D, U]
  const float* w_de = (const float*)d_in[4];   // [D, U]
  const float* nu   = (const float*)d_in[5];   // [U, 1]
  float* out = (float*)d_out;                  // [B, T_DE, T_EN]

  // ws layout (16 MB; verified available since r5)
  float* Et   = (float*)d_ws;                  // exp(2*en@w_en)^T [B][U][T_EN]
  float* de_t = Et + (size_t)B_ * U_ * T_EN_;  // exp(2*de@w_de)   [B*T_DE][U]
  short* p    = (short*)(de_t + (size_t)B_ * T_DE_ * U_);
  short* en_hi = p;                 p += 2097152;   // B*T_EN*D
  short* en_lo = p;                 p += 2097152;
  short* de_hi = p;                 p += 524288;    // B*T_DE*D
  short* de_lo = p;                 p += 524288;
  short* wen_hi = p;                p += 131072;    // D*U
  short* wen_lo = p;                p += 131072;
  short* wde_hi = p;                p += 131072;
  short* wde_lo = p;                p += 131072;

  prepack_kernel<<<dim3(1408), 256, 0, stream>>>(
      en, de, w_en, w_de, en_hi, en_lo, de_hi, de_lo,
      wen_hi, wen_lo, wde_hi, wde_lo);
  mfma_proj_kernel<<<dim3(640), 256, 0, stream>>>(
      en_hi, en_lo, de_hi, de_lo, wen_hi, wen_lo, wde_hi, wde_lo, Et, de_t);
  attn_mu_softmax_kernel<<<dim3(256), 512, 0, stream>>>(
      Et, de_t, nu, mask, out);
}